// Round 10
// baseline (542.470 us; speedup 1.0000x reference)
//
#include <hip/hip_runtime.h>
#include <hip/hip_bf16.h>

// IrrepLinear: out[b, o*25+m] = sum_i x[b, i*25+m] * W[l(m), o, i]  (+bias at m=0)
// r10: kill the barrier-lockstep (r2-r9 all plateau ~300us at 13k cycles/step
// with every pipe idle -> latency serialization at the per-step __syncthreads).
// Two streaming kernels:
//  k1: x fp32 [b][i*25+m] -> x_t bf16 [b][m][i]. Thread = (b, i-quad): 25
//      contiguous float4 (per-wave footprint 25.6KB < L1), static unroll
//      extraction, 25 coalesced 8B stores. No LDS, no barriers.
//  k2: GEMM with A-frags loaded DIRECTLY from global x_t (k-contiguous ->
//      1 dwordx4/frag; L1-shared across o-waves). Zero barriers in K-loop.
//      Proven r7 pieces: XCD sibling map, l-dedup B-frags, LDS epilogue.
// Fallback to r7 kernel if ws_size < 105MB.

typedef __bf16 bf16x8v __attribute__((ext_vector_type(8)));
typedef float floatx4 __attribute__((ext_vector_type(4)));
typedef unsigned short ushort_t;
typedef unsigned short ushortx4 __attribute__((ext_vector_type(4)));

#define ROW_F 12800          // floats per batch row (512*25)
#define XT_BYTES 104857600ULL  // 4096*25*512*2
#define PITCH 44             // (fallback kernel) ushorts per LDS A row

__device__ __forceinline__ ushort_t f2bf(float f) {
    __hip_bfloat16 h = __float2bfloat16(f);   // RNE
    return __builtin_bit_cast(ushort_t, h);
}

// weight fp32 [5][512][512] -> bf16 (same layout, k contiguous)
__global__ void cvt_w_kernel(const float* __restrict__ w, ushort_t* __restrict__ wb) {
    int i = (blockIdx.x * 256 + threadIdx.x) * 4;   // 1310720 elems, 1280x256 exact
    floatx4 v = *reinterpret_cast<const floatx4*>(w + i);
    ushortx4 h;
    h.x = f2bf(v[0]); h.y = f2bf(v[1]); h.z = f2bf(v[2]); h.w = f2bf(v[3]);
    *reinterpret_cast<ushortx4*>(wb + i) = h;
}

// ---- k1: transpose+convert x -> x_t[b][m][i] bf16 --------------------------
__global__ __launch_bounds__(256) void xpose_kernel(
        const float* __restrict__ x, ushort_t* __restrict__ xt) {
    int gid = blockIdx.x * 256 + threadIdx.x;   // 524288 = 4096 b x 128 ioq
    int b = gid >> 7, ioq = gid & 127;          // ioq: i-quad (4 i values)

    // slab: x[b][i*25+m], i in [4*ioq,4*ioq+4), m in [0,25) = 100 contiguous
    // floats at x + b*12800 + ioq*100. Lane stride 400B -> wave footprint
    // 25.6KB < 32KB L1: every 64B line fetched once, fully consumed.
    const floatx4* src = reinterpret_cast<const floatx4*>(x + (size_t)b * ROW_F + ioq * 100);
    floatx4 f4[25];
#pragma unroll
    for (int j = 0; j < 25; ++j) f4[j] = src[j];

    ushort_t* dst = xt + (size_t)b * 12800 + ioq * 4;
#pragma unroll
    for (int m = 0; m < 25; ++m) {              // static idx: (d*25+m) compile-time
        ushortx4 h;
#pragma unroll
        for (int d = 0; d < 4; ++d) {
            int idx = d * 25 + m;
            h[d] = f2bf(f4[idx >> 2][idx & 3]);
        }
        *reinterpret_cast<ushortx4*>(dst + (size_t)m * 512) = h;  // coalesced 8B
    }
}

// ---- k2: barrier-free GEMM from x_t ----------------------------------------
__global__ __launch_bounds__(256) void gemm_kernel(
        const ushort_t* __restrict__ xt, const ushort_t* __restrict__ wb,
        const float* __restrict__ bias, float* __restrict__ out) {
    __shared__ __align__(16) float ep[4 * 1608];   // epilogue only (25.7KB)

    const int tid = threadIdx.x, lane = tid & 63;
    const int wv = tid >> 6;                  // 4 waves = 4 o-slices of 16
    const int lr = lane & 15, lh = lane >> 4;

    // sibling-coresident same-XCD mapping (proven r7: FETCH 173MB)
    const int bid   = blockIdx.x;             // 2048 blocks
    const int osib  = (bid >> 3) & 7;
    const int btile = (bid & 7) | ((bid >> 6) << 3);
    const int b0 = btile * 16, o0 = osib * 64, ow = o0 + wv * 16;

    constexpr int LOF[25] = {0,1,1,1,2,2,2,2,2,3,3,3,3,3,3,3,4,4,4,4,4,4,4,4,4};

    floatx4 acc[25];
#pragma unroll
    for (int m = 0; m < 25; ++m) acc[m] = (floatx4){0.f, 0.f, 0.f, 0.f};

    // A row base: x_t[(b0+lr)*25 + m][k]; per step +32 ushorts.
    const ushort_t* abase = xt + (size_t)(b0 + lr) * 12800 + lh * 8;
    const ushort_t* bbase = wb + (size_t)(ow + lr) * 512 + lh * 8;

#pragma unroll 1
    for (int s = 0; s < 16; ++s) {
        const ushort_t* ab = abase + s * 32;
        const ushort_t* bb = bbase + s * 32;
        bf16x8v bfr[5];           // 5 l-deduped B-frags
#pragma unroll
        for (int l = 0; l < 5; ++l)
            bfr[l] = *reinterpret_cast<const bf16x8v*>(bb + (size_t)l * 262144);
#pragma unroll
        for (int m = 0; m < 25; ++m) {
            const bf16x8v a = *reinterpret_cast<const bf16x8v*>(ab + (size_t)m * 512);
            acc[m] = __builtin_amdgcn_mfma_f32_16x16x32_bf16(a, bfr[LOF[m]], acc[m], 0, 0, 0);
        }
    }

    // bias on the m=0 component only
    {
        float bv = bias[ow + lr];
#pragma unroll
        for (int r = 0; r < 4; ++r) acc[0][r] += bv;
    }

    // LDS-staged epilogue (proven: WRITE exactly 204.8MB), 4 passes x 4 b-rows
    constexpr int EPROW = 1608;
#pragma unroll 1
    for (int p = 0; p < 4; ++p) {
        __syncthreads();
        if (lh == p) {
#pragma unroll
            for (int m = 0; m < 25; ++m) {
                int cb = (wv * 16 + lr) * 25 + m;
#pragma unroll
                for (int r = 0; r < 4; ++r) ep[r * EPROW + cb] = acc[m][r];
            }
        }
        __syncthreads();
#pragma unroll 1
        for (int idx = tid; idx < 1600; idx += 256) {
            int rr = idx / 400, c4 = idx - rr * 400;
            floatx4 v = *reinterpret_cast<const floatx4*>(ep + rr * EPROW + c4 * 4);
            *reinterpret_cast<floatx4*>(
                out + (size_t)(b0 + p * 4 + rr) * ROW_F + o0 * 25 + c4 * 4) = v;
        }
    }
}

// ---- fallback (r7 kernel, used only if ws_size too small) ------------------
__global__ __launch_bounds__(256, 2) void irrep_fb_kernel(
        const float* __restrict__ x, const ushort_t* __restrict__ wb,
        const float* __restrict__ bias, float* __restrict__ out) {
    __shared__ __align__(16) ushort_t Asm[400 * PITCH];
    const int tid = threadIdx.x, lane = tid & 63;
    const int wv = tid >> 6, lr = lane & 15, lh = lane >> 4;
    const int bid = blockIdx.x;
    const int osib = (bid >> 3) & 7;
    const int btile = (bid & 7) | ((bid >> 6) << 3);
    const int b0 = btile * 16, o0 = osib * 64, ow = o0 + wv * 16;
    constexpr int LOF[25] = {0,1,1,1,2,2,2,2,2,3,3,3,3,3,3,3,4,4,4,4,4,4,4,4,4};
    const float* gp[13]; int woff[13];
#pragma unroll
    for (int i = 0; i < 13; ++i) {
        int Q = tid + 256 * i;
        if (Q < 3200) {
            int bb = Q / 200, r = Q - bb * 200;
            int kq = r / 25, m = r - kq * 25;
            gp[i] = x + (size_t)(b0 + bb) * ROW_F + kq * 100 + m;
            woff[i] = (bb * 25 + m) * PITCH + kq * 4;
        } else { gp[i] = x; woff[i] = 0; }
    }
    float vbuf[13][4];
    auto issue = [&]() {
#pragma unroll
        for (int i = 0; i < 13; ++i) if (tid + 256 * i < 3200) {
#pragma unroll
            for (int j = 0; j < 4; ++j) vbuf[i][j] = gp[i][j * 25];
            gp[i] += 800;
        }
    };
    auto scat = [&]() {
#pragma unroll
        for (int i = 0; i < 13; ++i) if (tid + 256 * i < 3200) {
            ushortx4 h;
#pragma unroll
            for (int j = 0; j < 4; ++j) h[j] = f2bf(vbuf[i][j]);
            *reinterpret_cast<ushortx4*>(&Asm[woff[i]]) = h;
        }
    };
    floatx4 acc[25];
#pragma unroll
    for (int m = 0; m < 25; ++m) acc[m] = (floatx4){0.f, 0.f, 0.f, 0.f};
    issue();
#pragma unroll 1
    for (int s = 0; s < 16; ++s) {
        __syncthreads();
        scat();
        __syncthreads();
        if (s < 15) issue();
        bf16x8v bfr[5];
#pragma unroll
        for (int l = 0; l < 5; ++l)
            bfr[l] = *reinterpret_cast<const bf16x8v*>(
                wb + (size_t)(l * 512 + ow + lr) * 512 + s * 32 + lh * 8);
#pragma unroll
        for (int m = 0; m < 25; ++m) {
            const bf16x8v a = *reinterpret_cast<const bf16x8v*>(
                &Asm[(lr * 25 + m) * PITCH + lh * 8]);
            acc[m] = __builtin_amdgcn_mfma_f32_16x16x32_bf16(a, bfr[LOF[m]], acc[m], 0, 0, 0);
        }
    }
    { float bv = bias[ow + lr];
#pragma unroll
      for (int r = 0; r < 4; ++r) acc[0][r] += bv; }
    float* ep = reinterpret_cast<float*>(Asm);
    constexpr int EPROW = 1608;
#pragma unroll 1
    for (int p = 0; p < 4; ++p) {
        __syncthreads();
        if (lh == p) {
#pragma unroll
            for (int m = 0; m < 25; ++m) {
                int cb = (wv * 16 + lr) * 25 + m;
#pragma unroll
                for (int r = 0; r < 4; ++r) ep[r * EPROW + cb] = acc[m][r];
            }
        }
        __syncthreads();
#pragma unroll 1
        for (int idx = tid; idx < 1600; idx += 256) {
            int rr = idx / 400, c4 = idx - rr * 400;
            floatx4 v = *reinterpret_cast<const floatx4*>(ep + rr * EPROW + c4 * 4);
            *reinterpret_cast<floatx4*>(
                out + (size_t)(b0 + p * 4 + rr) * ROW_F + o0 * 25 + c4 * 4) = v;
        }
    }
}

extern "C" void kernel_launch(void* const* d_in, const int* in_sizes, int n_in,
                              void* d_out, int out_size, void* d_ws, size_t ws_size,
                              hipStream_t stream) {
    const float* x    = (const float*)d_in[0];
    const float* w    = (const float*)d_in[1];
    const float* bias = (const float*)d_in[2];
    float* outp       = (float*)d_out;

    if (ws_size >= XT_BYTES + 2621440ULL + 256) {
        ushort_t* xt = (ushort_t*)d_ws;                          // 105MB
        ushort_t* wbp = (ushort_t*)((char*)d_ws + XT_BYTES);     // 2.62MB
        cvt_w_kernel<<<1280, 256, 0, stream>>>(w, wbp);
        xpose_kernel<<<2048, 256, 0, stream>>>(x, xt);
        gemm_kernel<<<2048, 256, 0, stream>>>(xt, wbp, bias, outp);
    } else {
        ushort_t* wbp = (ushort_t*)d_ws;
        cvt_w_kernel<<<1280, 256, 0, stream>>>(w, wbp);
        irrep_fb_kernel<<<2048, 256, 0, stream>>>(x, wbp, bias, outp);
    }
}

// Round 11
// 485.925 us; speedup vs baseline: 1.1164x; 1.1164x over previous
//
#include <hip/hip_runtime.h>
#include <hip/hip_bf16.h>

// IrrepLinear: out[b, o*25+m] = sum_i x[b, i*25+m] * W[l(m), o, i]  (+bias at m=0)
// r11 = r7 + register headroom + explicit pipelining. Diagnosis from r2-r10:
// every kernel had VGPR_Count=128 while acc[25] alone = 100 VGPRs -> compiler
// emitted load->waitcnt(0)->mfma serial chains (one exposed latency per A-frag,
// ~9-13k cy/step matches all measured plateaus). Fix: __launch_bounds__(256,1)
// (allow 256 VGPRs) + 8-deep rolling A-frag window + batched B loads.
// Proven pieces kept: r7 staging (pitch 44: writes 4/bank, reads 8/bank),
// sibling-coresident XCD map (FETCH 173MB), LDS epilogue (WRITE 204.8MB).

typedef __bf16 bf16x8v __attribute__((ext_vector_type(8)));
typedef float floatx4 __attribute__((ext_vector_type(4)));
typedef unsigned short ushort_t;
typedef unsigned short ushortx4 __attribute__((ext_vector_type(4)));

#define ROW_F 12800          // floats per batch row (512*25)
#define PITCH 44             // ushorts per LDS A row (88B)
#define LDS_USH (400 * 44)   // 35200 B

__device__ __forceinline__ ushort_t f2bf(float f) {
    __hip_bfloat16 h = __float2bfloat16(f);   // RNE
    return __builtin_bit_cast(ushort_t, h);
}

// weight fp32 [5][512][512] -> bf16 in ws (same layout, k contiguous)
__global__ void cvt_w_kernel(const float* __restrict__ w, ushort_t* __restrict__ wb) {
    int i = (blockIdx.x * 256 + threadIdx.x) * 4;   // 1310720 elems, 1280x256 exact
    floatx4 v = *reinterpret_cast<const floatx4*>(w + i);
    ushortx4 h;
    h.x = f2bf(v[0]); h.y = f2bf(v[1]); h.z = f2bf(v[2]); h.w = f2bf(v[3]);
    *reinterpret_cast<ushortx4*>(wb + i) = h;
}

__global__ __launch_bounds__(256, 1) void irrep_kernel(
        const float* __restrict__ x, const ushort_t* __restrict__ wb,
        const float* __restrict__ bias, float* __restrict__ out) {
    __shared__ __align__(16) ushort_t Asm[LDS_USH];

    const int tid = threadIdx.x, lane = tid & 63;
    const int wv = tid >> 6;                  // 4 waves = 4 o-slices of 16
    const int lr = lane & 15, lh = lane >> 4;

    // Sibling-coresident same-XCD mapping (proven r7: FETCH 173MB): all 8
    // o-siblings of a btile share bid%8 (one XCD) within a 64-bid window.
    const int bid   = blockIdx.x;             // 2048 blocks
    const int osib  = (bid >> 3) & 7;
    const int btile = (bid & 7) | ((bid >> 6) << 3);
    const int b0 = btile * 16, o0 = osib * 64, ow = o0 + wv * 16;

    constexpr int LOF[25] = {0,1,1,1,2,2,2,2,2,3,3,3,3,3,3,3,4,4,4,4,4,4,4,4,4};

    // ---- staging quads: Q = bb*200 + kq*25 + m (m fastest). 3200 quads/step.
    const float* gp[13]; int woff[13];
#pragma unroll
    for (int i = 0; i < 13; ++i) {
        int Q = tid + 256 * i;
        if (Q < 3200) {
            int bb = Q / 200, r = Q - bb * 200;
            int kq = r / 25, m = r - kq * 25;
            gp[i]  = x + (size_t)(b0 + bb) * ROW_F + kq * 100 + m;
            woff[i] = (bb * 25 + m) * PITCH + kq * 4;
        } else { gp[i] = x; woff[i] = 0; }
    }

    float vbuf[13][4];
    auto issue = [&]() {          // next step's x -> regs (independent loads)
#pragma unroll
        for (int i = 0; i < 13; ++i) if (tid + 256 * i < 3200) {
#pragma unroll
            for (int j = 0; j < 4; ++j) vbuf[i][j] = gp[i][j * 25];
            gp[i] += 800;         // advance one K32-step (32*25 floats)
        }
    };
    auto scat = [&]() {           // 13 x ds_write_b64, 4 accesses/bank
#pragma unroll
        for (int i = 0; i < 13; ++i) if (tid + 256 * i < 3200) {
            ushortx4 h;
#pragma unroll
            for (int j = 0; j < 4; ++j) h[j] = f2bf(vbuf[i][j]);
            *reinterpret_cast<ushortx4*>(&Asm[woff[i]]) = h;
        }
    };

    floatx4 acc[25];
#pragma unroll
    for (int m = 0; m < 25; ++m) acc[m] = (floatx4){0.f, 0.f, 0.f, 0.f};

    const ushort_t* arow = &Asm[lr * 25 * PITCH + lh * 8];   // + m*PITCH per frag

    issue();                      // stage step 0
#pragma unroll 1
    for (int s = 0; s < 16; ++s) {
        __syncthreads();          // previous step's A-reads done
        scat();                   // uses vbuf of step s
        __syncthreads();          // tile visible
        if (s < 15) issue();      // next step's 52 loads in flight under compute

        bf16x8v bfr[5];           // 5 l-deduped B-frags, batch-issued
#pragma unroll
        for (int l = 0; l < 5; ++l)
            bfr[l] = *reinterpret_cast<const bf16x8v*>(
                wb + (size_t)(l * 512 + ow + lr) * 512 + s * 32 + lh * 8);

        // 8-deep rolling A-frag window: ~8 ds_reads outstanding at all times
        // (fully unrolled -> all afr indices compile-time constant).
        bf16x8v afr[8];
#pragma unroll
        for (int m = 0; m < 8; ++m)
            afr[m] = *reinterpret_cast<const bf16x8v*>(arow + m * PITCH);
#pragma unroll
        for (int m = 0; m < 25; ++m) {
            const bf16x8v a = afr[m & 7];
            if (m + 8 < 25)
                afr[m & 7] = *reinterpret_cast<const bf16x8v*>(arow + (m + 8) * PITCH);
            acc[m] = __builtin_amdgcn_mfma_f32_16x16x32_bf16(a, bfr[LOF[m]], acc[m], 0, 0, 0);
        }
    }

    // bias on the m=0 component only
    {
        float bv = bias[ow + lr];
#pragma unroll
        for (int r = 0; r < 4; ++r) acc[0][r] += bv;
    }

    // ---- LDS-staged epilogue: 4 passes x 4 b-rows; global stores = contiguous
    // 6.4KB float4 runs (keeps WRITE_SIZE at exactly 204.8MB).
    float* ep = reinterpret_cast<float*>(Asm);
    constexpr int EPROW = 1608;   // 1600 + 8 pad
#pragma unroll 1
    for (int p = 0; p < 4; ++p) {
        __syncthreads();          // k-loop reads / prior pass reads done
        if (lh == p) {            // D rows = lh*4 + r -> rows 4p..4p+3
#pragma unroll
            for (int m = 0; m < 25; ++m) {
                int cb = (wv * 16 + lr) * 25 + m;
#pragma unroll
                for (int r = 0; r < 4; ++r) ep[r * EPROW + cb] = acc[m][r];
            }
        }
        __syncthreads();
#pragma unroll 1
        for (int idx = tid; idx < 1600; idx += 256) {
            int rr = idx / 400, c4 = idx - rr * 400;
            floatx4 v = *reinterpret_cast<const floatx4*>(ep + rr * EPROW + c4 * 4);
            *reinterpret_cast<floatx4*>(
                out + (size_t)(b0 + p * 4 + rr) * ROW_F + o0 * 25 + c4 * 4) = v;
        }
    }
}

extern "C" void kernel_launch(void* const* d_in, const int* in_sizes, int n_in,
                              void* d_out, int out_size, void* d_ws, size_t ws_size,
                              hipStream_t stream) {
    const float* x    = (const float*)d_in[0];
    const float* w    = (const float*)d_in[1];
    const float* bias = (const float*)d_in[2];
    float* outp       = (float*)d_out;
    ushort_t* wb      = (ushort_t*)d_ws;    // 2.62 MB bf16 weights

    cvt_w_kernel<<<1280, 256, 0, stream>>>(w, wb);
    irrep_kernel<<<2048, 256, 0, stream>>>(x, wb, bias, outp);
}